// Round 1
// baseline (677.688 us; speedup 1.0000x reference)
//
#include <hip/hip_runtime.h>
#include <math.h>

#define TT   16
#define BB   64
#define DG   256
#define DH   512
#define DOUT 256
#define NSET 3

// ---------- block reduction helpers (512 threads = 8 waves) ----------
__device__ __forceinline__ float blk_sum(float v, float* red, int tid) {
#pragma unroll
    for (int off = 32; off > 0; off >>= 1) v += __shfl_down(v, off, 64);
    if ((tid & 63) == 0) red[tid >> 6] = v;
    __syncthreads();
    float s = ((red[0] + red[1]) + (red[2] + red[3])) +
              ((red[4] + red[5]) + (red[6] + red[7]));
    __syncthreads();
    return s;
}

__device__ __forceinline__ float2 blk_sum2(float a, float b, float* red, int tid) {
#pragma unroll
    for (int off = 32; off > 0; off >>= 1) {
        a += __shfl_down(a, off, 64);
        b += __shfl_down(b, off, 64);
    }
    if ((tid & 63) == 0) { red[tid >> 6] = a; red[8 + (tid >> 6)] = b; }
    __syncthreads();
    float sa = ((red[0] + red[1]) + (red[2] + red[3])) +
               ((red[4] + red[5]) + (red[6] + red[7]));
    float sb = ((red[8] + red[9]) + (red[10] + red[11])) +
               ((red[12] + red[13]) + (red[14] + red[15]));
    __syncthreads();
    return make_float2(sa, sb);
}

// ---------- kernel 1: zproj[t][b][:] = z[t][b][:] @ W_g^T ----------
// grid: 256 blocks = 64 batches x 4 column-chunks; block: 128 threads
__global__ __launch_bounds__(128) void zproj_kernel(
    const float* __restrict__ z,    // [T][B][DG]
    const float* __restrict__ Wg,   // [DH][DG]
    float* __restrict__ zp)         // [T][B][DH]
{
    __shared__ __align__(16) float zb[TT * DG];   // 16 KB: z[:, b, :]
    const int bq  = blockIdx.x;
    const int b   = bq >> 2;
    const int q   = bq & 3;
    const int tid = threadIdx.x;

    for (int r = tid; r < TT * (DG / 4); r += 128) {
        int t  = r >> 6;          // / (DG/4)
        int i4 = r & 63;
        ((float4*)zb)[r] = ((const float4*)(z + ((size_t)t * BB + b) * DG))[i4];
    }
    __syncthreads();

    const int j = q * 128 + tid;
    const float4* __restrict__ wr = (const float4*)(Wg + (size_t)j * DG);
    float acc[TT];
#pragma unroll
    for (int t = 0; t < TT; ++t) acc[t] = 0.f;

    for (int i4 = 0; i4 < DG / 4; ++i4) {
        float4 w = wr[i4];
#pragma unroll
        for (int t = 0; t < TT; ++t) {
            float4 zz = ((const float4*)zb)[t * (DG / 4) + i4];
            acc[t] += w.x * zz.x + w.y * zz.y + w.z * zz.z + w.w * zz.w;
        }
    }
#pragma unroll
    for (int t = 0; t < TT; ++t)
        zp[((size_t)t * BB + b) * DH + j] = acc[t];
}

// ---------- kernel 2: the full recurrence, one block per batch ----------
__global__ __launch_bounds__(512) void rnn_main(
    const float* __restrict__ zp,      // [T][B][DH]
    const float* __restrict__ Wh,      // [DH][DH]
    const float* __restrict__ bh,      // [DH]
    const float* __restrict__ lng,     // [DH]
    const float* __restrict__ lnb,     // [DH]
    const float* __restrict__ alphap,  // [1]
    const float* __restrict__ Whead,   // [DOUT][DH]
    const float* __restrict__ bhead,   // [DOUT]
    const float* __restrict__ clean,   // [B][DOUT]
    float* __restrict__ out_ssd,       // [B]
    float* __restrict__ out_cos)       // [B]
{
    __shared__ __align__(16) float hs[DH];            // current h_s
    __shared__ __align__(16) float u[(TT - 1) * DH];  // stored Hebbian vectors (rank-15 A)
    __shared__ __align__(16) float ppart[DH];
    __shared__ float red[16];
    __shared__ float dres[16];
    __shared__ float cvec[16];                        // coefficients c_i = eta * lambda^age

    const int tid  = threadIdx.x;
    const int b    = blockIdx.x;
    const int lane = tid & 63;
    const int wid  = tid >> 6;

    const float al   = alphap[0];
    const float kexp = (al >= 0.f) ? (1.f + log1pf(expf(al)))
                                   : (1.f / (1.f + log1pf(expf(-al))));

    const float gj  = lng[tid];
    const float bj  = lnb[tid];
    const float bhj = bh[tid];
    const float4* __restrict__ wrow = (const float4*)(Wh + (size_t)tid * DH);

    for (int t = 0; t < TT; ++t) {
        // ---- h_base[tid] = b_h + zproj + (h_prev @ W_h^T) ----
        float hb = bhj + zp[((size_t)t * BB + b) * DH + tid];
        if (t > 0) {
#pragma unroll 4
            for (int i4 = 0; i4 < DH / 4; ++i4) {
                float4 w  = wrow[i4];
                float4 h4 = ((const float4*)hs)[i4];   // LDS broadcast
                hb += w.x * h4.x + w.y * h4.y + w.z * h4.z + w.w * h4.w;
            }
        }
        // ---- h = relu(LN(hb)) (two-pass LN like reference) ----
        float mu  = blk_sum(hb, red, tid) * (1.f / DH);
        float dx  = hb - mu;
        float var = blk_sum(dx * dx, red, tid) * (1.f / DH);
        float h   = fmaxf(dx * rsqrtf(var + 1e-5f) * gj + bj, 0.f);
        hs[tid] = h;
        __syncthreads();

        if (t < TT - 1) {
            // ---- inner settle loop with alpha blending ----
            for (int s = 0; s < NSET; ++s) {
                // dots d_i = u_i . h_s (tasks 0..t-1), task t: h_s . h_s
                const int ntask = t + 1;
                for (int task = wid; task < ntask; task += 8) {
                    const float* uv = (task == t) ? hs : (u + task * DH);
                    float acc = 0.f;
#pragma unroll
                    for (int c8 = 0; c8 < 8; ++c8) {
                        int idx = lane + (c8 << 6);
                        acc += uv[idx] * hs[idx];
                    }
#pragma unroll
                    for (int off = 32; off > 0; off >>= 1) acc += __shfl_down(acc, off, 64);
                    if (lane == 0) dres[task] = acc;
                }
                __syncthreads();

                // Ah[tid] = sum_i c_i d_i u_i[tid]
                float Ah = 0.f;
                for (int i = 0; i < t; ++i) Ah += cvec[i] * dres[i] * u[i * DH + tid];

                float2 dn = blk_sum2(h * Ah, Ah * Ah, red, tid);  // (h.Ah, |Ah|^2)
                float hh = dres[t];
                float n1 = fmaxf(sqrtf(hh), 1e-6f);
                float n2 = fmaxf(sqrtf(dn.y), 1e-6f);
                float R  = fminf(fmaxf(dn.x / (n1 * n2), 0.f), 1.f);
                float aa = 1.f - powf(1.f - R, kexp);

                float x    = (1.f - aa * aa) * hb + aa * Ah;
                float mu2  = blk_sum(x, red, tid) * (1.f / DH);
                float dx2  = x - mu2;
                float var2 = blk_sum(dx2 * dx2, red, tid) * (1.f / DH);
                h = fmaxf(dx2 * rsqrtf(var2 + 1e-5f) * gj + bj, 0.f);
                hs[tid] = h;
                __syncthreads();
            }
            // ---- Hebbian update: decay coefficients, append new vector ----
            u[t * DH + tid] = h;
            if (tid < 16) {
                if (tid < t)       cvec[tid] *= 0.95f;
                else if (tid == t) cvec[tid] = 0.5f;
            }
            __syncthreads();
        } else {
            // ---- final query step: h = relu(LN(hb + Ah)), no blending ----
            for (int s = 0; s < NSET; ++s) {
                const int ntask = TT - 1;
                for (int task = wid; task < ntask; task += 8) {
                    const float* uv = u + task * DH;
                    float acc = 0.f;
#pragma unroll
                    for (int c8 = 0; c8 < 8; ++c8) {
                        int idx = lane + (c8 << 6);
                        acc += uv[idx] * hs[idx];
                    }
#pragma unroll
                    for (int off = 32; off > 0; off >>= 1) acc += __shfl_down(acc, off, 64);
                    if (lane == 0) dres[task] = acc;
                }
                __syncthreads();

                float Ah = 0.f;
#pragma unroll
                for (int i = 0; i < TT - 1; ++i) Ah += cvec[i] * dres[i] * u[i * DH + tid];

                float x    = hb + Ah;
                float mu2  = blk_sum(x, red, tid) * (1.f / DH);
                float dx2  = x - mu2;
                float var2 = blk_sum(dx2 * dx2, red, tid) * (1.f / DH);
                h = fmaxf(dx2 * rsqrtf(var2 + 1e-5f) * gj + bj, 0.f);
                hs[tid] = h;
                __syncthreads();
            }
        }
    }

    // ---- head: pred = h @ W_head^T + b_head; per-batch loss partials ----
    {
        const int oj   = tid & 255;
        const int half = tid >> 8;
        const float4* wr = (const float4*)(Whead + (size_t)oj * DH + half * 256);
        const float4* hv = ((const float4*)hs) + half * 64;
        float acc = 0.f;
#pragma unroll 4
        for (int i4 = 0; i4 < 64; ++i4) {
            float4 w  = wr[i4];
            float4 h4 = hv[i4];
            acc += w.x * h4.x + w.y * h4.y + w.z * h4.z + w.w * h4.w;
        }
        ppart[tid] = acc;
        __syncthreads();

        float pred = 0.f, tg = 0.f;
        if (tid < DOUT) {
            pred = ppart[tid] + ppart[tid + 256] + bhead[tid];
            tg   = clean[(size_t)b * DOUT + tid];
        }
        float pss = blk_sum(pred * pred, red, tid);
        float tss = blk_sum(tg * tg, red, tid);
        float pn = pred / (sqrtf(pss) + 1e-6f);
        float tn = tg   / (sqrtf(tss) + 1e-6f);
        float d  = pn - tn;
        float2 lc = blk_sum2(d * d, pn * tn, red, tid);
        if (tid == 0) { out_ssd[b] = lc.x; out_cos[b] = lc.y; }
    }
}

// ---------- kernel 3: reduce 64 batch partials -> (loss, cosine) ----------
__global__ __launch_bounds__(64) void finish_kernel(
    const float* __restrict__ ssd, const float* __restrict__ cosv,
    float* __restrict__ out)
{
    int tid = threadIdx.x;
    float a = ssd[tid];
    float c = cosv[tid];
#pragma unroll
    for (int off = 32; off > 0; off >>= 1) {
        a += __shfl_down(a, off, 64);
        c += __shfl_down(c, off, 64);
    }
    if (tid == 0) {
        out[0] = a / (float)(BB * DOUT);  // mean over [B, DOUT]
        out[1] = c / (float)BB;           // mean over batch
    }
}

extern "C" void kernel_launch(void* const* d_in, const int* in_sizes, int n_in,
                              void* d_out, int out_size, void* d_ws, size_t ws_size,
                              hipStream_t stream) {
    const float* z      = (const float*)d_in[0];  // [16,64,256]
    const float* clean  = (const float*)d_in[1];  // [64,256]
    const float* Wh     = (const float*)d_in[2];  // [512,512]
    const float* Wg     = (const float*)d_in[3];  // [512,256]
    const float* bh     = (const float*)d_in[4];  // [512]
    const float* lng    = (const float*)d_in[5];  // [512]
    const float* lnb    = (const float*)d_in[6];  // [512]
    const float* alpha  = (const float*)d_in[7];  // [1]
    const float* Whead  = (const float*)d_in[8];  // [256,512]
    const float* bhead  = (const float*)d_in[9];  // [256]
    float* out = (float*)d_out;

    float* zp   = (float*)d_ws;                   // T*B*DH floats = 2 MB
    float* ssd  = zp + (size_t)TT * BB * DH;      // 64 floats
    float* cosv = ssd + BB;                       // 64 floats

    zproj_kernel<<<BB * 4, 128, 0, stream>>>(z, Wg, zp);
    rnn_main<<<BB, 512, 0, stream>>>(zp, Wh, bh, lng, lnb, alpha,
                                     Whead, bhead, clean, ssd, cosv);
    finish_kernel<<<1, 64, 0, stream>>>(ssd, cosv, out);
}

// Round 2
// 466.690 us; speedup vs baseline: 1.4521x; 1.4521x over previous
//
#include <hip/hip_runtime.h>
#include <math.h>

#define TT   16
#define BB   64
#define DG   256
#define DH   512
#define DOUT 256

// ---------- block reduction helpers (512 threads = 8 waves) ----------
__device__ __forceinline__ float blk_sum(float v, float* red, int tid) {
#pragma unroll
    for (int off = 32; off > 0; off >>= 1) v += __shfl_down(v, off, 64);
    if ((tid & 63) == 0) red[tid >> 6] = v;
    __syncthreads();
    float s = ((red[0] + red[1]) + (red[2] + red[3])) +
              ((red[4] + red[5]) + (red[6] + red[7]));
    __syncthreads();
    return s;
}

__device__ __forceinline__ float2 blk_sum2(float a, float b, float* red, int tid) {
#pragma unroll
    for (int off = 32; off > 0; off >>= 1) {
        a += __shfl_down(a, off, 64);
        b += __shfl_down(b, off, 64);
    }
    if ((tid & 63) == 0) { red[tid >> 6] = a; red[8 + (tid >> 6)] = b; }
    __syncthreads();
    float sa = ((red[0] + red[1]) + (red[2] + red[3])) +
               ((red[4] + red[5]) + (red[6] + red[7]));
    float sb = ((red[8] + red[9]) + (red[10] + red[11])) +
               ((red[12] + red[13]) + (red[14] + red[15]));
    __syncthreads();
    return make_float2(sa, sb);
}

template<int N>
__device__ __forceinline__ void blk_sumN(float* v, float* red, int tid) {
#pragma unroll
    for (int off = 32; off > 0; off >>= 1)
#pragma unroll
        for (int n = 0; n < N; ++n) v[n] += __shfl_down(v[n], off, 64);
    if ((tid & 63) == 0) {
#pragma unroll
        for (int n = 0; n < N; ++n) red[(tid >> 6) * N + n] = v[n];
    }
    __syncthreads();
#pragma unroll
    for (int n = 0; n < N; ++n) {
        float s = 0.f;
#pragma unroll
        for (int w = 0; w < 8; ++w) s += red[w * N + n];
        v[n] = s;
    }
    __syncthreads();
}

// ---------- kernel 1: zproj[t][b][:] = z[t][b][:] @ W_g^T  (64 blocks x 512) ----------
__global__ __launch_bounds__(512) void zproj2(
    const float* __restrict__ z,    // [T][B][DG]
    const float* __restrict__ Wg,   // [DH][DG]
    float* __restrict__ zp)         // [T][B][DH]
{
    __shared__ __align__(16) float4 zb4[TT * 64];   // z[:, b, :] 16 KB
    const int b = blockIdx.x, tid = threadIdx.x;
    {
        int f = tid;
        zb4[f] = ((const float4*)z)[((size_t)(f >> 6) * BB + b) * 64 + (f & 63)];
        f = tid + 512;
        zb4[f] = ((const float4*)z)[((size_t)(f >> 6) * BB + b) * 64 + (f & 63)];
    }
    __syncthreads();
    const float4* wr = (const float4*)(Wg + (size_t)tid * DG);
    float acc[TT];
#pragma unroll
    for (int t = 0; t < TT; ++t) acc[t] = 0.f;
    for (int c4 = 0; c4 < 64; ++c4) {
        float4 w = wr[c4];
#pragma unroll
        for (int t = 0; t < TT; ++t) {
            float4 zz = zb4[(t << 6) + c4];
            acc[t] += w.x * zz.x + w.y * zz.y + w.z * zz.z + w.w * zz.w;
        }
    }
#pragma unroll
    for (int t = 0; t < TT; ++t)
        zp[((size_t)t * BB + b) * DH + tid] = acc[t];
}

// ---------- kernel 2: recurrence, 4 blocks per batch (column-split W_h in VGPRs) ----------
__global__ __launch_bounds__(512, 2) void rnn2(
    const float* __restrict__ zp,      // [T][B][DH]
    const float* Wh,                   // [DH][DH] (no __restrict__: keep loads un-rematerializable)
    const float* __restrict__ bh,
    const float* __restrict__ lng,
    const float* __restrict__ lnb,
    const float* __restrict__ alphap,
    const float* __restrict__ Whead,   // [DOUT][DH]
    const float* __restrict__ bhead,
    const float* __restrict__ clean,   // [B][DOUT]
    float* gpart,                      // [2][B][4][DH] hb partial exchange
    int* cnt,                          // [B] monotonic barrier counters (zeroed per call)
    float* __restrict__ ssd, float* __restrict__ cosv)
{
    __shared__ __align__(16) float hs[DH];
    __shared__ __align__(16) float u_lds[(TT - 1) * DH];  // 30 KB: rank-15 A factors
    __shared__ __align__(16) float ppart[DH];
    __shared__ float red[32];
    __shared__ float dres[16];
    __shared__ float cvec[16];

    const int tid  = threadIdx.x;
    const int b    = blockIdx.x & 63;   // blocks {b, b+64, b+128, b+192} -> same XCD
    const int q    = blockIdx.x >> 6;   // column strip
    const int lane = tid & 63;
    const int wid  = tid >> 6;

    const float al   = alphap[0];
    const float kexp = (al >= 0.f) ? (1.f + log1pf(expf(al)))
                                   : (1.f / (1.f + log1pf(expf(-al))));
    const float gj   = lng[tid];
    const float lnbj = lnb[tid];
    const float bhj  = bh[tid];

    // register-resident W_h strip: row tid, cols [128q, 128q+128)  (128 VGPRs)
    float4 wh4[32];
    {
        const float4* src = (const float4*)(Wh + (size_t)tid * DH + (q << 7));
#pragma unroll
        for (int k = 0; k < 32; ++k) wh4[k] = src[k];
    }

    hs[tid] = 0.f;
    if (tid < 16) cvec[tid] = 0.f;
    __syncthreads();

    float hb = 0.f, h = 0.f, S_hb = 0.f, S_hb2 = 0.f;

    for (int t = 0; t < TT; ++t) {
        // ---- partial matvec from registers (hb_q[tid] = W_h[tid, strip] . h[strip]) ----
        float acc = 0.f;
#pragma unroll
        for (int k = 0; k < 32; ++k) {
            float4 h4 = ((const float4*)hs)[(q << 5) + k];   // uniform broadcast
            acc += wh4[k].x * h4.x + wh4[k].y * h4.y + wh4[k].z * h4.z + wh4[k].w * h4.w;
        }
        {
            float* gq = gpart + (((size_t)(t & 1) * BB + b) * 4 + q) * DH;
            __hip_atomic_store(&gq[tid], acc, __ATOMIC_RELAXED, __HIP_MEMORY_SCOPE_AGENT);
        }
        // ---- 4-block barrier (monotonic counter; parity double-buffer makes reuse safe) ----
        __syncthreads();                    // drains vmcnt: stores complete
        if (tid == 0) {
            __threadfence();
            __hip_atomic_fetch_add(&cnt[b], 1, __ATOMIC_RELEASE, __HIP_MEMORY_SCOPE_AGENT);
            const int target = 4 * (t + 1);
            while (__hip_atomic_load(&cnt[b], __ATOMIC_ACQUIRE, __HIP_MEMORY_SCOPE_AGENT) < target) {}
            __threadfence();                // invalidate L1 before block reads partials
        }
        __syncthreads();

        {
            const float* gb = gpart + ((size_t)(t & 1) * BB + b) * 4 * DH;
            float p0 = __hip_atomic_load(&gb[tid],            __ATOMIC_RELAXED, __HIP_MEMORY_SCOPE_AGENT);
            float p1 = __hip_atomic_load(&gb[DH + tid],       __ATOMIC_RELAXED, __HIP_MEMORY_SCOPE_AGENT);
            float p2 = __hip_atomic_load(&gb[2 * DH + tid],   __ATOMIC_RELAXED, __HIP_MEMORY_SCOPE_AGENT);
            float p3 = __hip_atomic_load(&gb[3 * DH + tid],   __ATOMIC_RELAXED, __HIP_MEMORY_SCOPE_AGENT);
            hb = ((p0 + p1) + (p2 + p3)) + zp[((size_t)t * BB + b) * DH + tid] + bhj;
        }

        // ---- base LN (one-pass stats) ----
        {
            float v2[2] = {hb, hb * hb};
            blk_sumN<2>(v2, red, tid);
            S_hb = v2[0]; S_hb2 = v2[1];
            float mu  = S_hb * (1.f / DH);
            float var = S_hb2 * (1.f / DH) - mu * mu;
            h = fmaxf((hb - mu) * rsqrtf(var + 1e-5f) * gj + lnbj, 0.f);
            hs[tid] = h;
            __syncthreads();
        }

        const bool fin   = (t == TT - 1);
        const int  ntask = fin ? (TT - 1) : (t + 1);   // dots + (self-norm unless final)
        const int  nu    = fin ? (TT - 1) : t;
        for (int s = 0; s < 3; ++s) {
            // dots d_i = u_i . h  (task t = |h|^2 when !fin); wave-parallel
            for (int task = wid; task < ntask; task += 8) {
                const float* uv = (!fin && task == t) ? hs : (u_lds + (task << 9));
                float a8 = 0.f;
#pragma unroll
                for (int c8 = 0; c8 < 8; ++c8) {
                    int idx = lane + (c8 << 6);
                    a8 += uv[idx] * hs[idx];
                }
#pragma unroll
                for (int off = 32; off > 0; off >>= 1) a8 += __shfl_down(a8, off, 64);
                if (lane == 0) dres[task] = a8;
            }
            __syncthreads();

            float Ah = 0.f;
            for (int i = 0; i < nu; ++i) Ah += cvec[i] * dres[i] * u_lds[(i << 9) + tid];

            float v4[4] = {h * Ah, Ah * Ah, hb * Ah, Ah};
            blk_sumN<4>(v4, red, tid);

            float aa, c1;
            if (!fin) {
                float n1 = fmaxf(sqrtf(dres[t]), 1e-6f);
                float n2 = fmaxf(sqrtf(v4[1]), 1e-6f);
                float R  = fminf(fmaxf(v4[0] / (n1 * n2), 0.f), 1.f);
                aa = 1.f - powf(1.f - R, kexp);
                c1 = 1.f - aa * aa;
            } else { aa = 1.f; c1 = 1.f; }

            // LN stats of x = c1*hb + aa*Ah via bilinear expansion (no extra reduction)
            float Sx   = c1 * S_hb + aa * v4[3];
            float Sx2  = c1 * c1 * S_hb2 + 2.f * c1 * aa * v4[2] + aa * aa * v4[1];
            float mu2  = Sx * (1.f / DH);
            float var2 = Sx2 * (1.f / DH) - mu2 * mu2;
            float x    = c1 * hb + aa * Ah;
            h = fmaxf((x - mu2) * rsqrtf(var2 + 1e-5f) * gj + lnbj, 0.f);
            hs[tid] = h;
            __syncthreads();
        }
        if (!fin) {
            u_lds[(t << 9) + tid] = h;      // append Hebbian factor
            if (tid < TT - 1) {
                float cv = cvec[tid];
                cvec[tid] = (tid < t) ? cv * 0.95f : (tid == t ? 0.5f : cv);
            }
            __syncthreads();
        }
    }

    if (q != 0) return;

    // ---- head + per-batch loss partials (q==0 blocks only) ----
    {
        const int oj   = tid & 255;
        const int half = tid >> 8;
        const float4* wr = (const float4*)(Whead + (size_t)oj * DH + half * 256);
        const float4* hv = ((const float4*)hs) + half * 64;
        float acc = 0.f;
#pragma unroll 4
        for (int i4 = 0; i4 < 64; ++i4) {
            float4 w  = wr[i4];
            float4 h4 = hv[i4];
            acc += w.x * h4.x + w.y * h4.y + w.z * h4.z + w.w * h4.w;
        }
        ppart[tid] = acc;
        __syncthreads();

        float pred = 0.f, tg = 0.f;
        if (tid < DOUT) {
            pred = ppart[tid] + ppart[tid + 256] + bhead[tid];
            tg   = clean[(size_t)b * DOUT + tid];
        }
        float pss = blk_sum(pred * pred, red, tid);
        float tss = blk_sum(tg * tg, red, tid);
        float pn = pred / (sqrtf(pss) + 1e-6f);
        float tn = tg   / (sqrtf(tss) + 1e-6f);
        float d  = pn - tn;
        float2 lc = blk_sum2(d * d, pn * tn, red, tid);
        if (tid == 0) { ssd[b] = lc.x; cosv[b] = lc.y; }
    }
}

// ---------- kernel 3: reduce 64 batch partials -> (loss, cosine) ----------
__global__ __launch_bounds__(64) void finish_kernel(
    const float* __restrict__ ssd, const float* __restrict__ cosv,
    float* __restrict__ out)
{
    int tid = threadIdx.x;
    float a = ssd[tid];
    float c = cosv[tid];
#pragma unroll
    for (int off = 32; off > 0; off >>= 1) {
        a += __shfl_down(a, off, 64);
        c += __shfl_down(c, off, 64);
    }
    if (tid == 0) {
        out[0] = a / (float)(BB * DOUT);
        out[1] = c / (float)BB;
    }
}

extern "C" void kernel_launch(void* const* d_in, const int* in_sizes, int n_in,
                              void* d_out, int out_size, void* d_ws, size_t ws_size,
                              hipStream_t stream) {
    const float* z     = (const float*)d_in[0];
    const float* clean = (const float*)d_in[1];
    const float* Wh    = (const float*)d_in[2];
    const float* Wg    = (const float*)d_in[3];
    const float* bh    = (const float*)d_in[4];
    const float* lng   = (const float*)d_in[5];
    const float* lnb   = (const float*)d_in[6];
    const float* alpha = (const float*)d_in[7];
    const float* Whead = (const float*)d_in[8];
    const float* bhead = (const float*)d_in[9];
    float* out = (float*)d_out;

    float* zp    = (float*)d_ws;                       // 16*64*512 floats = 2 MB
    float* gpart = zp + (size_t)TT * BB * DH;          // 2*64*4*512 floats = 1 MB
    float* ssd   = gpart + (size_t)2 * BB * 4 * DH;    // 64
    float* cosv  = ssd + BB;                           // 64
    int*   cnt   = (int*)(cosv + BB);                  // 64 ints

    hipMemsetAsync(cnt, 0, BB * sizeof(int), stream);
    zproj2<<<BB, 512, 0, stream>>>(z, Wg, zp);
    rnn2<<<4 * BB, 512, 0, stream>>>(zp, Wh, bh, lng, lnb, alpha,
                                     Whead, bhead, clean, gpart, cnt, ssd, cosv);
    finish_kernel<<<1, 64, 0, stream>>>(ssd, cosv, out);
}

// Round 3
// 378.825 us; speedup vs baseline: 1.7889x; 1.2319x over previous
//
#include <hip/hip_runtime.h>
#include <math.h>

#define TT   16
#define BB   64
#define DG   256
#define DH   512
#define DOUT 256

// ---------- helpers ----------
__device__ __forceinline__ float blk_sum(float v, float* red, int tid) {
#pragma unroll
    for (int off = 32; off > 0; off >>= 1) v += __shfl_down(v, off, 64);
    if ((tid & 63) == 0) red[tid >> 6] = v;
    __syncthreads();
    float s = ((red[0] + red[1]) + (red[2] + red[3])) +
              ((red[4] + red[5]) + (red[6] + red[7]));
    __syncthreads();
    return s;
}

__device__ __forceinline__ float2 blk_sum2(float a, float b, float* red, int tid) {
#pragma unroll
    for (int off = 32; off > 0; off >>= 1) {
        a += __shfl_down(a, off, 64);
        b += __shfl_down(b, off, 64);
    }
    if ((tid & 63) == 0) { red[tid >> 6] = a; red[8 + (tid >> 6)] = b; }
    __syncthreads();
    float sa = ((red[0] + red[1]) + (red[2] + red[3])) +
               ((red[4] + red[5]) + (red[6] + red[7]));
    float sb = ((red[8] + red[9]) + (red[10] + red[11])) +
               ((red[12] + red[13]) + (red[14] + red[15]));
    __syncthreads();
    return make_float2(sa, sb);
}

// ---------- kernel 1: zproj[t][b][:] = z[t][b][:] @ W_g^T  (64 blocks x 512) ----------
__global__ __launch_bounds__(512) void zproj2(
    const float* __restrict__ z,    // [T][B][DG]
    const float* __restrict__ Wg,   // [DH][DG]
    float* __restrict__ zp)         // [T][B][DH]
{
    __shared__ __align__(16) float4 zb4[TT * 64];   // z[:, b, :] 16 KB
    const int b = blockIdx.x, tid = threadIdx.x;
    {
        int f = tid;
        zb4[f] = ((const float4*)z)[((size_t)(f >> 6) * BB + b) * 64 + (f & 63)];
        f = tid + 512;
        zb4[f] = ((const float4*)z)[((size_t)(f >> 6) * BB + b) * 64 + (f & 63)];
    }
    __syncthreads();
    const float4* wr = (const float4*)(Wg + (size_t)tid * DG);
    float acc[TT];
#pragma unroll
    for (int t = 0; t < TT; ++t) acc[t] = 0.f;
    for (int c4 = 0; c4 < 64; ++c4) {
        float4 w = wr[c4];
#pragma unroll
        for (int t = 0; t < TT; ++t) {
            float4 zz = zb4[(t << 6) + c4];
            acc[t] += w.x * zz.x + w.y * zz.y + w.z * zz.z + w.w * zz.w;
        }
    }
#pragma unroll
    for (int t = 0; t < TT; ++t)
        zp[((size_t)t * BB + b) * DH + tid] = acc[t];
}

// ---------- kernel 2: recurrence. 4 blocks/batch; W_h strip pinned in AGPRs;
//            wave 0 runs the whole settle chain barrier-free. ----------
__global__ __launch_bounds__(512, 2) void rnn3(
    const float* __restrict__ zp,      // [T][B][DH]
    const float* __restrict__ Wh,      // [DH][DH]
    const float* __restrict__ bh,
    const float* __restrict__ lng,
    const float* __restrict__ lnb,
    const float* __restrict__ alphap,
    const float* __restrict__ Whead,   // [DOUT][DH]
    const float* __restrict__ bhead,
    const float* __restrict__ clean,   // [B][DOUT]
    float* gpart,                      // [2][B][4][DH] exchange buffers
    int* cnt,                          // [B] monotonic counters (zeroed per call)
    float* __restrict__ ssd, float* __restrict__ cosv)
{
    __shared__ __align__(16) float hs[DH];
    __shared__ __align__(16) float u_lds[(TT - 1) * DH];  // 30 KB rank-15 A factors
    __shared__ __align__(16) float hb_lds[DH];
    __shared__ __align__(16) float ppart[DH];
    __shared__ float red[16];

    const int tid  = threadIdx.x;
    const int b    = blockIdx.x & 63;
    const int q    = blockIdx.x >> 6;   // column strip
    const int lane = tid & 63;
    const int wid  = tid >> 6;

    const float al   = alphap[0];
    const float kexp = (al >= 0.f) ? (1.f + log1pf(expf(al)))
                                   : (1.f / (1.f + log1pf(expf(-al))));
    const float bhj  = bh[tid];

    // ---- W_h strip row=tid, cols [128q,128q+128): pinned into 128 AGPRs ----
    float wa[128];
    {
        const float* src = Wh + (size_t)tid * DH + (q << 7);
#pragma unroll
        for (int k = 0; k < 128; k += 4) {
            float4 v = *(const float4*)(src + k);
            asm volatile("v_accvgpr_write_b32 %0, %1" : "=a"(wa[k + 0]) : "v"(v.x));
            asm volatile("v_accvgpr_write_b32 %0, %1" : "=a"(wa[k + 1]) : "v"(v.y));
            asm volatile("v_accvgpr_write_b32 %0, %1" : "=a"(wa[k + 2]) : "v"(v.z));
            asm volatile("v_accvgpr_write_b32 %0, %1" : "=a"(wa[k + 3]) : "v"(v.w));
        }
    }

    // wave-0 per-lane constants: dims lane+64k
    float gj8[8], bj8[8];
    if (wid == 0) {
#pragma unroll
        for (int k = 0; k < 8; ++k) {
            gj8[k] = lng[lane + 64 * k];
            bj8[k] = lnb[lane + 64 * k];
        }
    }
    float cv[TT - 1];
#pragma unroll
    for (int i = 0; i < TT - 1; ++i) cv[i] = 0.f;

    hs[tid] = 0.f;
    __syncthreads();

#pragma unroll 1
    for (int t = 0; t < TT; ++t) {
        // early zp load (hides under matvec + barrier)
        float zv = zp[((size_t)t * BB + b) * DH + tid];

        // ---- partial matvec from AGPRs: acc = W_h[tid, strip] . h[strip] ----
        float acc = 0.f;
#pragma unroll
        for (int k4 = 0; k4 < 32; ++k4) {
            float4 h4 = ((const float4*)hs)[(q << 5) + k4];   // uniform broadcast
            float w0, w1, w2, w3;
            asm("v_accvgpr_read_b32 %0, %1" : "=v"(w0) : "a"(wa[4 * k4 + 0]));
            asm("v_accvgpr_read_b32 %0, %1" : "=v"(w1) : "a"(wa[4 * k4 + 1]));
            asm("v_accvgpr_read_b32 %0, %1" : "=v"(w2) : "a"(wa[4 * k4 + 2]));
            asm("v_accvgpr_read_b32 %0, %1" : "=v"(w3) : "a"(wa[4 * k4 + 3]));
            acc = fmaf(w0, h4.x, fmaf(w1, h4.y, fmaf(w2, h4.z, fmaf(w3, h4.w, acc))));
        }
        __hip_atomic_store(gpart + (((size_t)(t & 1) * BB + b) * 4 + q) * DH + tid, acc,
                           __ATOMIC_RELAXED, __HIP_MEMORY_SCOPE_AGENT);
        __syncthreads();   // B1: all stores vmcnt-drained (reach coherence point)
        if (tid == 0) {
            __hip_atomic_fetch_add(&cnt[b], 1, __ATOMIC_RELEASE, __HIP_MEMORY_SCOPE_AGENT);
            const int target = 4 * (t + 1);
            while (__hip_atomic_load(&cnt[b], __ATOMIC_ACQUIRE, __HIP_MEMORY_SCOPE_AGENT) < target) {}
        }
        __syncthreads();   // B2: exchange complete
        {
            const float* gb = gpart + ((size_t)(t & 1) * BB + b) * 4 * DH;
            float p0 = __hip_atomic_load(gb + tid,          __ATOMIC_RELAXED, __HIP_MEMORY_SCOPE_AGENT);
            float p1 = __hip_atomic_load(gb + DH + tid,     __ATOMIC_RELAXED, __HIP_MEMORY_SCOPE_AGENT);
            float p2 = __hip_atomic_load(gb + 2 * DH + tid, __ATOMIC_RELAXED, __HIP_MEMORY_SCOPE_AGENT);
            float p3 = __hip_atomic_load(gb + 3 * DH + tid, __ATOMIC_RELAXED, __HIP_MEMORY_SCOPE_AGENT);
            hb_lds[tid] = ((p0 + p1) + (p2 + p3)) + zv + bhj;
        }
        __syncthreads();   // B3: hb published

        // ---- wave 0: base LN + full settle, barrier-free ----
        if (wid == 0) {
            float hbr[8], h8[8];
#pragma unroll
            for (int k = 0; k < 8; ++k) hbr[k] = hb_lds[lane + 64 * k];
            float s1 = 0.f, s2 = 0.f;
#pragma unroll
            for (int k = 0; k < 8; ++k) { s1 += hbr[k]; s2 = fmaf(hbr[k], hbr[k], s2); }
#pragma unroll
            for (int m = 32; m > 0; m >>= 1) {
                s1 += __shfl_xor(s1, m, 64);
                s2 += __shfl_xor(s2, m, 64);
            }
            const float S_hb = s1, S_hb2 = s2;
            {
                float mu  = s1 * (1.f / DH);
                float var = s2 * (1.f / DH) - mu * mu;
                float rs  = rsqrtf(var + 1e-5f);
#pragma unroll
                for (int k = 0; k < 8; ++k)
                    h8[k] = fmaxf((hbr[k] - mu) * rs * gj8[k] + bj8[k], 0.f);
            }

            const bool fin = (t == TT - 1);
            const int  nu  = fin ? (TT - 1) : t;

#pragma unroll 1
            for (int s = 0; s < 3; ++s) {
                // dots d_i = cv_i * (u_i . h)   (static unroll, uniform predicate)
                float d[TT - 1];
#pragma unroll
                for (int i = 0; i < TT - 1; ++i) {
                    d[i] = 0.f;
                    if (i < nu) {
                        float a = 0.f;
#pragma unroll
                        for (int k = 0; k < 8; ++k)
                            a = fmaf(u_lds[i * DH + lane + 64 * k], h8[k], a);
#pragma unroll
                        for (int m = 32; m > 0; m >>= 1) a += __shfl_xor(a, m, 64);
                        d[i] = a * cv[i];
                    }
                }
                // Ah = sum_i d_i u_i
                float Ah8[8];
#pragma unroll
                for (int k = 0; k < 8; ++k) Ah8[k] = 0.f;
#pragma unroll
                for (int i = 0; i < TT - 1; ++i) {
                    if (i < nu) {
#pragma unroll
                        for (int k = 0; k < 8; ++k)
                            Ah8[k] = fmaf(d[i], u_lds[i * DH + lane + 64 * k], Ah8[k]);
                    }
                }
                // fused 5-sum butterfly
                float hAh = 0.f, AhAh = 0.f, hbAh = 0.f, SAh = 0.f, hh = 0.f;
#pragma unroll
                for (int k = 0; k < 8; ++k) {
                    hAh  = fmaf(h8[k],  Ah8[k], hAh);
                    AhAh = fmaf(Ah8[k], Ah8[k], AhAh);
                    hbAh = fmaf(hbr[k], Ah8[k], hbAh);
                    SAh += Ah8[k];
                    hh   = fmaf(h8[k],  h8[k],  hh);
                }
#pragma unroll
                for (int m = 32; m > 0; m >>= 1) {
                    hAh  += __shfl_xor(hAh,  m, 64);
                    AhAh += __shfl_xor(AhAh, m, 64);
                    hbAh += __shfl_xor(hbAh, m, 64);
                    SAh  += __shfl_xor(SAh,  m, 64);
                    hh   += __shfl_xor(hh,   m, 64);
                }
                float aa, c1;
                if (!fin) {
                    float n1 = fmaxf(sqrtf(hh),   1e-6f);
                    float n2 = fmaxf(sqrtf(AhAh), 1e-6f);
                    float R  = fminf(fmaxf(hAh / (n1 * n2), 0.f), 1.f);
                    aa = 1.f - __builtin_amdgcn_exp2f(kexp * __builtin_amdgcn_logf(1.f - R));
                    c1 = 1.f - aa * aa;
                } else { aa = 1.f; c1 = 1.f; }
                // LN stats of x = c1*hb + aa*Ah via bilinear expansion
                float Sx   = c1 * S_hb + aa * SAh;
                float Sx2  = c1 * c1 * S_hb2 + 2.f * c1 * aa * hbAh + aa * aa * AhAh;
                float mu2  = Sx * (1.f / DH);
                float var2 = Sx2 * (1.f / DH) - mu2 * mu2;
                float rs2  = rsqrtf(var2 + 1e-5f);
#pragma unroll
                for (int k = 0; k < 8; ++k) {
                    float x = c1 * hbr[k] + aa * Ah8[k];
                    h8[k] = fmaxf((x - mu2) * rs2 * gj8[k] + bj8[k], 0.f);
                }
            }
            // publish h_s; append Hebbian factor; decay coefficients
#pragma unroll
            for (int k = 0; k < 8; ++k) hs[lane + 64 * k] = h8[k];
            if (!fin) {
#pragma unroll
                for (int k = 0; k < 8; ++k) u_lds[t * DH + lane + 64 * k] = h8[k];
#pragma unroll
                for (int i = 0; i < TT - 1; ++i) {
                    if (i < t)       cv[i] *= 0.95f;
                    else if (i == t) cv[i] = 0.5f;
                }
            }
        }
        __syncthreads();   // B4: hs ready for next matvec
    }

    if (q != 0) return;

    // ---- head + per-batch loss partials (q==0 blocks only) ----
    {
        const int oj   = tid & 255;
        const int half = tid >> 8;
        const float4* wr = (const float4*)(Whead + (size_t)oj * DH + half * 256);
        const float4* hv = ((const float4*)hs) + half * 64;
        float acc = 0.f;
#pragma unroll 4
        for (int i4 = 0; i4 < 64; ++i4) {
            float4 w  = wr[i4];
            float4 h4 = hv[i4];
            acc += w.x * h4.x + w.y * h4.y + w.z * h4.z + w.w * h4.w;
        }
        ppart[tid] = acc;
        __syncthreads();

        float pred = 0.f, tg = 0.f;
        if (tid < DOUT) {
            pred = ppart[tid] + ppart[tid + 256] + bhead[tid];
            tg   = clean[(size_t)b * DOUT + tid];
        }
        float pss = blk_sum(pred * pred, red, tid);
        float tss = blk_sum(tg * tg, red, tid);
        float pn = pred / (sqrtf(pss) + 1e-6f);
        float tn = tg   / (sqrtf(tss) + 1e-6f);
        float dd = pn - tn;
        float2 lc = blk_sum2(dd * dd, pn * tn, red, tid);
        if (tid == 0) { ssd[b] = lc.x; cosv[b] = lc.y; }
    }
}

// ---------- kernel 3: reduce 64 batch partials -> (loss, cosine) ----------
__global__ __launch_bounds__(64) void finish_kernel(
    const float* __restrict__ ssd, const float* __restrict__ cosv,
    float* __restrict__ out)
{
    int tid = threadIdx.x;
    float a = ssd[tid];
    float c = cosv[tid];
#pragma unroll
    for (int off = 32; off > 0; off >>= 1) {
        a += __shfl_down(a, off, 64);
        c += __shfl_down(c, off, 64);
    }
    if (tid == 0) {
        out[0] = a / (float)(BB * DOUT);
        out[1] = c / (float)BB;
    }
}

extern "C" void kernel_launch(void* const* d_in, const int* in_sizes, int n_in,
                              void* d_out, int out_size, void* d_ws, size_t ws_size,
                              hipStream_t stream) {
    const float* z     = (const float*)d_in[0];
    const float* clean = (const float*)d_in[1];
    const float* Wh    = (const float*)d_in[2];
    const float* Wg    = (const float*)d_in[3];
    const float* bh    = (const float*)d_in[4];
    const float* lng   = (const float*)d_in[5];
    const float* lnb   = (const float*)d_in[6];
    const float* alpha = (const float*)d_in[7];
    const float* Whead = (const float*)d_in[8];
    const float* bhead = (const float*)d_in[9];
    float* out = (float*)d_out;

    float* zp    = (float*)d_ws;                       // 2 MB
    float* gpart = zp + (size_t)TT * BB * DH;          // 1 MB
    float* ssd   = gpart + (size_t)2 * BB * 4 * DH;    // 64
    float* cosv  = ssd + BB;                           // 64
    int*   cnt   = (int*)(cosv + BB);                  // 64 ints

    hipMemsetAsync(cnt, 0, BB * sizeof(int), stream);
    zproj2<<<BB, 512, 0, stream>>>(z, Wg, zp);
    rnn3<<<4 * BB, 512, 0, stream>>>(zp, Wh, bh, lng, lnb, alpha,
                                     Whead, bhead, clean, gpart, cnt, ssd, cosv);
    finish_kernel<<<1, 64, 0, stream>>>(ssd, cosv, out);
}

// Round 4
// 322.455 us; speedup vs baseline: 2.1017x; 1.1748x over previous
//
#include <hip/hip_runtime.h>
#include <math.h>

#define TT   16
#define BB   64
#define DG   256
#define DH   512
#define DOUT 256
#define CNTPAD 32   // 128-byte spacing between per-batch counters

// ---------- helpers ----------
__device__ __forceinline__ float blk_sum(float v, float* red, int tid) {
#pragma unroll
    for (int off = 32; off > 0; off >>= 1) v += __shfl_down(v, off, 64);
    if ((tid & 63) == 0) red[tid >> 6] = v;
    __syncthreads();
    float s = ((red[0] + red[1]) + (red[2] + red[3])) +
              ((red[4] + red[5]) + (red[6] + red[7]));
    __syncthreads();
    return s;
}

__device__ __forceinline__ float2 blk_sum2(float a, float b, float* red, int tid) {
#pragma unroll
    for (int off = 32; off > 0; off >>= 1) {
        a += __shfl_down(a, off, 64);
        b += __shfl_down(b, off, 64);
    }
    if ((tid & 63) == 0) { red[tid >> 6] = a; red[8 + (tid >> 6)] = b; }
    __syncthreads();
    float sa = ((red[0] + red[1]) + (red[2] + red[3])) +
               ((red[4] + red[5]) + (red[6] + red[7]));
    float sb = ((red[8] + red[9]) + (red[10] + red[11])) +
               ((red[12] + red[13]) + (red[14] + red[15]));
    __syncthreads();
    return make_float2(sa, sb);
}

__device__ __forceinline__ float dot4(float4 a, float4 b) {
    return fmaf(a.x, b.x, fmaf(a.y, b.y, fmaf(a.z, b.z, a.w * b.w)));
}

// ---------- kernel 1: zproj[t][b][:] = z[t][b][:] @ W_g^T; also zeroes counters ----------
__global__ __launch_bounds__(512) void zproj2(
    const float* __restrict__ z,    // [T][B][DG]
    const float* __restrict__ Wg,   // [DH][DG]
    float* __restrict__ zp,         // [T][B][DH]
    int* cnt)
{
    __shared__ __align__(16) float4 zb4[TT * 64];   // z[:, b, :] 16 KB
    const int b = blockIdx.x, tid = threadIdx.x;
    if (tid == 0)
        __hip_atomic_store(cnt + b * CNTPAD, 0, __ATOMIC_RELAXED, __HIP_MEMORY_SCOPE_AGENT);
    {
        int f = tid;
        zb4[f] = ((const float4*)z)[((size_t)(f >> 6) * BB + b) * 64 + (f & 63)];
        f = tid + 512;
        zb4[f] = ((const float4*)z)[((size_t)(f >> 6) * BB + b) * 64 + (f & 63)];
    }
    __syncthreads();
    const float4* wr = (const float4*)(Wg + (size_t)tid * DG);
    float acc[TT];
#pragma unroll
    for (int t = 0; t < TT; ++t) acc[t] = 0.f;
    for (int c4 = 0; c4 < 64; ++c4) {
        float4 w = wr[c4];
#pragma unroll
        for (int t = 0; t < TT; ++t) {
            float4 zz = zb4[(t << 6) + c4];
            acc[t] += w.x * zz.x + w.y * zz.y + w.z * zz.z + w.w * zz.w;
        }
    }
#pragma unroll
    for (int t = 0; t < TT; ++t)
        zp[((size_t)t * BB + b) * DH + tid] = acc[t];
}

// ---------- kernel 2: recurrence. 4 blocks/batch; W_h strip in AGPRs;
//            relaxed-only cross-block exchange; wave 0 runs settle barrier-free ----------
__global__ __launch_bounds__(512, 2) void rnn4(
    const float* __restrict__ zp,      // [T][B][DH]
    const float* __restrict__ Wh,      // [DH][DH]
    const float* __restrict__ bh,
    const float* __restrict__ lng,
    const float* __restrict__ lnb,
    const float* __restrict__ alphap,
    const float* __restrict__ Whead,   // [DOUT][DH]
    const float* __restrict__ bhead,
    const float* __restrict__ clean,   // [B][DOUT]
    float* gpart,                      // [2][B][4][DH] exchange buffers
    int* cnt,                          // padded counters (zeroed by zproj2)
    float* __restrict__ ssd, float* __restrict__ cosv)
{
    __shared__ __align__(16) float hs[DH];
    __shared__ __align__(16) float u_lds[(TT - 1) * DH];  // 30 KB rank-15 A factors
    __shared__ __align__(16) float hb_lds[DH];
    __shared__ __align__(16) float ppart[DH];
    __shared__ float red[16];

    const int tid  = threadIdx.x;
    const int b    = blockIdx.x & 63;
    const int q    = blockIdx.x >> 6;   // column strip
    const int lane = tid & 63;
    const int wid  = tid >> 6;

    const float al   = alphap[0];
    const float kexp = (al >= 0.f) ? (1.f + log1pf(expf(al)))
                                   : (1.f / (1.f + log1pf(expf(-al))));
    const float bhj  = bh[tid];
    int* cnt_b = cnt + b * CNTPAD;

    // ---- W_h strip row=tid, cols [128q,128q+128): pinned into 128 AGPRs ----
    float wa[128];
    {
        const float* src = Wh + (size_t)tid * DH + (q << 7);
#pragma unroll
        for (int k = 0; k < 128; k += 4) {
            float4 v = *(const float4*)(src + k);
            asm volatile("v_accvgpr_write_b32 %0, %1" : "=a"(wa[k + 0]) : "v"(v.x));
            asm volatile("v_accvgpr_write_b32 %0, %1" : "=a"(wa[k + 1]) : "v"(v.y));
            asm volatile("v_accvgpr_write_b32 %0, %1" : "=a"(wa[k + 2]) : "v"(v.z));
            asm volatile("v_accvgpr_write_b32 %0, %1" : "=a"(wa[k + 3]) : "v"(v.w));
        }
    }

    // wave-0 per-lane constants; register layout: dim = 256*c + 4*lane + e
    float4 gj4[2], bj4[2];
    if (wid == 0) {
#pragma unroll
        for (int c = 0; c < 2; ++c) {
            gj4[c] = *(const float4*)(lng + 256 * c + 4 * lane);
            bj4[c] = *(const float4*)(lnb + 256 * c + 4 * lane);
        }
    }
    float cv[TT - 1];
#pragma unroll
    for (int i = 0; i < TT - 1; ++i) cv[i] = 0.f;

    hs[tid] = 0.f;
    __syncthreads();

#pragma unroll 1
    for (int t = 0; t < TT; ++t) {
        float zv = zp[((size_t)t * BB + b) * DH + tid];

        if (t > 0) {
            // ---- partial matvec from AGPRs ----
            float acc = 0.f;
#pragma unroll
            for (int k4 = 0; k4 < 32; ++k4) {
                float4 h4 = ((const float4*)hs)[(q << 5) + k4];   // uniform broadcast
                float w0, w1, w2, w3;
                asm("v_accvgpr_read_b32 %0, %1" : "=v"(w0) : "a"(wa[4 * k4 + 0]));
                asm("v_accvgpr_read_b32 %0, %1" : "=v"(w1) : "a"(wa[4 * k4 + 1]));
                asm("v_accvgpr_read_b32 %0, %1" : "=v"(w2) : "a"(wa[4 * k4 + 2]));
                asm("v_accvgpr_read_b32 %0, %1" : "=v"(w3) : "a"(wa[4 * k4 + 3]));
                acc = fmaf(w0, h4.x, fmaf(w1, h4.y, fmaf(w2, h4.z, fmaf(w3, h4.w, acc))));
            }
            __hip_atomic_store(gpart + (((size_t)(t & 1) * BB + b) * 4 + q) * DH + tid, acc,
                               __ATOMIC_RELAXED, __HIP_MEMORY_SCOPE_AGENT);
            __syncthreads();   // B1: compiler's vmcnt(0) drain -> stores at coherence point
            if (tid == 0) {
                int old = __hip_atomic_fetch_add(cnt_b, 1, __ATOMIC_RELAXED, __HIP_MEMORY_SCOPE_AGENT);
                if (old != 4 * t - 1) {   // not last: poll (relaxed, backoff)
                    while (__hip_atomic_load(cnt_b, __ATOMIC_RELAXED, __HIP_MEMORY_SCOPE_AGENT) < 4 * t)
                        __builtin_amdgcn_s_sleep(1);
                }
            }
            __syncthreads();   // B2: exchange complete
            {
                const float* gb = gpart + ((size_t)(t & 1) * BB + b) * 4 * DH;
                float p0 = __hip_atomic_load(gb + tid,          __ATOMIC_RELAXED, __HIP_MEMORY_SCOPE_AGENT);
                float p1 = __hip_atomic_load(gb + DH + tid,     __ATOMIC_RELAXED, __HIP_MEMORY_SCOPE_AGENT);
                float p2 = __hip_atomic_load(gb + 2 * DH + tid, __ATOMIC_RELAXED, __HIP_MEMORY_SCOPE_AGENT);
                float p3 = __hip_atomic_load(gb + 3 * DH + tid, __ATOMIC_RELAXED, __HIP_MEMORY_SCOPE_AGENT);
                hb_lds[tid] = ((p0 + p1) + (p2 + p3)) + zv + bhj;
            }
        } else {
            hb_lds[tid] = zv + bhj;       // h0 = 0 -> no matvec, no exchange
        }
        __syncthreads();   // B3: hb published

        // ---- wave 0: base LN + settle, barrier-free, b128 LDS access ----
        if (wid == 0) {
            float4 hbr[2], hv[2];
            hbr[0] = *(const float4*)&hb_lds[4 * lane];
            hbr[1] = *(const float4*)&hb_lds[256 + 4 * lane];
            float s1 = 0.f, s2 = 0.f;
#pragma unroll
            for (int c = 0; c < 2; ++c) {
                s1 += hbr[c].x + hbr[c].y + hbr[c].z + hbr[c].w;
                s2 += dot4(hbr[c], hbr[c]);
            }
#pragma unroll
            for (int m = 32; m > 0; m >>= 1) {
                s1 += __shfl_xor(s1, m, 64);
                s2 += __shfl_xor(s2, m, 64);
            }
            const float S_hb = s1, S_hb2 = s2;
            {
                float mu  = s1 * (1.f / DH);
                float var = s2 * (1.f / DH) - mu * mu;
                float rs  = rsqrtf(var + 1e-5f);
#pragma unroll
                for (int c = 0; c < 2; ++c) {
                    hv[c].x = fmaxf((hbr[c].x - mu) * rs * gj4[c].x + bj4[c].x, 0.f);
                    hv[c].y = fmaxf((hbr[c].y - mu) * rs * gj4[c].y + bj4[c].y, 0.f);
                    hv[c].z = fmaxf((hbr[c].z - mu) * rs * gj4[c].z + bj4[c].z, 0.f);
                    hv[c].w = fmaxf((hbr[c].w - mu) * rs * gj4[c].w + bj4[c].w, 0.f);
                }
            }

            const bool fin = (t == TT - 1);
            const int  nu  = fin ? (TT - 1) : t;

            if (t > 0) {     // t==0 settle is an exact identity (A=0)
#pragma unroll 1
                for (int s = 0; s < 3; ++s) {
                    float d[TT - 1];
#pragma unroll
                    for (int i = 0; i < TT - 1; ++i) {
                        d[i] = 0.f;
                        if (i < nu) {
                            float4 u0 = *(const float4*)&u_lds[i * DH + 4 * lane];
                            float4 u1 = *(const float4*)&u_lds[i * DH + 256 + 4 * lane];
                            float a = dot4(u0, hv[0]) + dot4(u1, hv[1]);
#pragma unroll
                            for (int m = 32; m > 0; m >>= 1) a += __shfl_xor(a, m, 64);
                            d[i] = a * cv[i];
                        }
                    }
                    float4 Ah[2];
                    Ah[0] = make_float4(0.f, 0.f, 0.f, 0.f);
                    Ah[1] = make_float4(0.f, 0.f, 0.f, 0.f);
#pragma unroll
                    for (int i = 0; i < TT - 1; ++i) {
                        if (i < nu) {
                            float4 u0 = *(const float4*)&u_lds[i * DH + 4 * lane];
                            float4 u1 = *(const float4*)&u_lds[i * DH + 256 + 4 * lane];
                            Ah[0].x = fmaf(d[i], u0.x, Ah[0].x); Ah[0].y = fmaf(d[i], u0.y, Ah[0].y);
                            Ah[0].z = fmaf(d[i], u0.z, Ah[0].z); Ah[0].w = fmaf(d[i], u0.w, Ah[0].w);
                            Ah[1].x = fmaf(d[i], u1.x, Ah[1].x); Ah[1].y = fmaf(d[i], u1.y, Ah[1].y);
                            Ah[1].z = fmaf(d[i], u1.z, Ah[1].z); Ah[1].w = fmaf(d[i], u1.w, Ah[1].w);
                        }
                    }
                    float hAh = 0.f, AhAh = 0.f, hbAh = 0.f, SAh = 0.f, hh = 0.f;
#pragma unroll
                    for (int c = 0; c < 2; ++c) {
                        hAh  += dot4(hv[c],  Ah[c]);
                        AhAh += dot4(Ah[c],  Ah[c]);
                        hbAh += dot4(hbr[c], Ah[c]);
                        SAh  += Ah[c].x + Ah[c].y + Ah[c].z + Ah[c].w;
                        hh   += dot4(hv[c],  hv[c]);
                    }
#pragma unroll
                    for (int m = 32; m > 0; m >>= 1) {
                        hAh  += __shfl_xor(hAh,  m, 64);
                        AhAh += __shfl_xor(AhAh, m, 64);
                        hbAh += __shfl_xor(hbAh, m, 64);
                        SAh  += __shfl_xor(SAh,  m, 64);
                        hh   += __shfl_xor(hh,   m, 64);
                    }
                    float aa, c1;
                    if (!fin) {
                        float n1 = fmaxf(sqrtf(hh),   1e-6f);
                        float n2 = fmaxf(sqrtf(AhAh), 1e-6f);
                        float R  = fminf(fmaxf(hAh / (n1 * n2), 0.f), 1.f);
                        aa = 1.f - __builtin_amdgcn_exp2f(kexp * __builtin_amdgcn_logf(1.f - R));
                        c1 = 1.f - aa * aa;
                    } else { aa = 1.f; c1 = 1.f; }
                    float Sx   = c1 * S_hb + aa * SAh;
                    float Sx2  = c1 * c1 * S_hb2 + 2.f * c1 * aa * hbAh + aa * aa * AhAh;
                    float mu2  = Sx * (1.f / DH);
                    float var2 = Sx2 * (1.f / DH) - mu2 * mu2;
                    float rs2  = rsqrtf(var2 + 1e-5f);
#pragma unroll
                    for (int c = 0; c < 2; ++c) {
                        float x0 = c1 * hbr[c].x + aa * Ah[c].x;
                        float x1 = c1 * hbr[c].y + aa * Ah[c].y;
                        float x2 = c1 * hbr[c].z + aa * Ah[c].z;
                        float x3 = c1 * hbr[c].w + aa * Ah[c].w;
                        hv[c].x = fmaxf((x0 - mu2) * rs2 * gj4[c].x + bj4[c].x, 0.f);
                        hv[c].y = fmaxf((x1 - mu2) * rs2 * gj4[c].y + bj4[c].y, 0.f);
                        hv[c].z = fmaxf((x2 - mu2) * rs2 * gj4[c].z + bj4[c].z, 0.f);
                        hv[c].w = fmaxf((x3 - mu2) * rs2 * gj4[c].w + bj4[c].w, 0.f);
                    }
                }
            }
            // publish h_s; append Hebbian factor; decay coefficients
            *(float4*)&hs[4 * lane]        = hv[0];
            *(float4*)&hs[256 + 4 * lane]  = hv[1];
            if (!fin) {
                *(float4*)&u_lds[t * DH + 4 * lane]       = hv[0];
                *(float4*)&u_lds[t * DH + 256 + 4 * lane] = hv[1];
#pragma unroll
                for (int i = 0; i < TT - 1; ++i) {
                    if (i < t)       cv[i] *= 0.95f;
                    else if (i == t) cv[i] = 0.5f;
                }
            }
        }
        __syncthreads();   // B4: hs ready for next matvec
    }

    if (q != 0) return;

    // ---- head + per-batch loss partials (q==0 blocks only) ----
    {
        const int oj   = tid & 255;
        const int half = tid >> 8;
        const float4* wr = (const float4*)(Whead + (size_t)oj * DH + half * 256);
        const float4* hvv = ((const float4*)hs) + half * 64;
        float acc = 0.f;
#pragma unroll 4
        for (int i4 = 0; i4 < 64; ++i4) {
            float4 w  = wr[i4];
            float4 h4 = hvv[i4];
            acc += w.x * h4.x + w.y * h4.y + w.z * h4.z + w.w * h4.w;
        }
        ppart[tid] = acc;
        __syncthreads();

        float pred = 0.f, tg = 0.f;
        if (tid < DOUT) {
            pred = ppart[tid] + ppart[tid + 256] + bhead[tid];
            tg   = clean[(size_t)b * DOUT + tid];
        }
        float pss = blk_sum(pred * pred, red, tid);
        float tss = blk_sum(tg * tg, red, tid);
        float pn = pred / (sqrtf(pss) + 1e-6f);
        float tn = tg   / (sqrtf(tss) + 1e-6f);
        float dd = pn - tn;
        float2 lc = blk_sum2(dd * dd, pn * tn, red, tid);
        if (tid == 0) { ssd[b] = lc.x; cosv[b] = lc.y; }
    }
}

// ---------- kernel 3: reduce 64 batch partials -> (loss, cosine) ----------
__global__ __launch_bounds__(64) void finish_kernel(
    const float* __restrict__ ssd, const float* __restrict__ cosv,
    float* __restrict__ out)
{
    int tid = threadIdx.x;
    float a = ssd[tid];
    float c = cosv[tid];
#pragma unroll
    for (int off = 32; off > 0; off >>= 1) {
        a += __shfl_down(a, off, 64);
        c += __shfl_down(c, off, 64);
    }
    if (tid == 0) {
        out[0] = a / (float)(BB * DOUT);
        out[1] = c / (float)BB;
    }
}

extern "C" void kernel_launch(void* const* d_in, const int* in_sizes, int n_in,
                              void* d_out, int out_size, void* d_ws, size_t ws_size,
                              hipStream_t stream) {
    const float* z     = (const float*)d_in[0];
    const float* clean = (const float*)d_in[1];
    const float* Wh    = (const float*)d_in[2];
    const float* Wg    = (const float*)d_in[3];
    const float* bh    = (const float*)d_in[4];
    const float* lng   = (const float*)d_in[5];
    const float* lnb   = (const float*)d_in[6];
    const float* alpha = (const float*)d_in[7];
    const float* Whead = (const float*)d_in[8];
    const float* bhead = (const float*)d_in[9];
    float* out = (float*)d_out;

    float* zp    = (float*)d_ws;                       // 2 MB
    float* gpart = zp + (size_t)TT * BB * DH;          // 1 MB
    float* ssd   = gpart + (size_t)2 * BB * 4 * DH;    // 64
    float* cosv  = ssd + BB;                           // 64
    int*   cnt   = (int*)(cosv + BB);                  // 64*CNTPAD ints (8 KB)

    zproj2<<<BB, 512, 0, stream>>>(z, Wg, zp, cnt);
    rnn4<<<4 * BB, 512, 0, stream>>>(zp, Wh, bh, lng, lnb, alpha,
                                     Whead, bhead, clean, gpart, cnt, ssd, cosv);
    finish_kernel<<<1, 64, 0, stream>>>(ssd, cosv, out);
}

// Round 5
// 271.249 us; speedup vs baseline: 2.4984x; 1.1888x over previous
//
#include <hip/hip_runtime.h>
#include <math.h>

#define TT   16
#define BB   64
#define DG   256
#define DH   512
#define DOUT 256
#define FPAD 32   // 128-byte spacing between flags

// ---------- helpers (epilogue only) ----------
__device__ __forceinline__ float blk_sum(float v, float* red, int tid) {
#pragma unroll
    for (int off = 32; off > 0; off >>= 1) v += __shfl_down(v, off, 64);
    if ((tid & 63) == 0) red[tid >> 6] = v;
    __syncthreads();
    float s = ((red[0] + red[1]) + (red[2] + red[3])) +
              ((red[4] + red[5]) + (red[6] + red[7]));
    __syncthreads();
    return s;
}

__device__ __forceinline__ float2 blk_sum2(float a, float b, float* red, int tid) {
#pragma unroll
    for (int off = 32; off > 0; off >>= 1) {
        a += __shfl_down(a, off, 64);
        b += __shfl_down(b, off, 64);
    }
    if ((tid & 63) == 0) { red[tid >> 6] = a; red[8 + (tid >> 6)] = b; }
    __syncthreads();
    float sa = ((red[0] + red[1]) + (red[2] + red[3])) +
               ((red[4] + red[5]) + (red[6] + red[7]));
    float sb = ((red[8] + red[9]) + (red[10] + red[11])) +
               ((red[12] + red[13]) + (red[14] + red[15]));
    __syncthreads();
    return make_float2(sa, sb);
}

__device__ __forceinline__ float dot4(float4 a, float4 b) {
    return fmaf(a.x, b.x, fmaf(a.y, b.y, fmaf(a.z, b.z, a.w * b.w)));
}

// ---------- kernel 1: zproj[t][b][:] = z[t][b][:] @ W_g^T; zero flags ----------
__global__ __launch_bounds__(512) void zproj2(
    const float* __restrict__ z,    // [T][B][DG]
    const float* __restrict__ Wg,   // [DH][DG]
    float* __restrict__ zp,         // [T][B][DH]
    int* flags)
{
    __shared__ __align__(16) float4 zb4[TT * 64];   // z[:, b, :] 16 KB
    const int b = blockIdx.x, tid = threadIdx.x;
    if (tid < 4)
        __hip_atomic_store(flags + (b * 4 + tid) * FPAD, 0, __ATOMIC_RELAXED, __HIP_MEMORY_SCOPE_AGENT);
    {
        int f = tid;
        zb4[f] = ((const float4*)z)[((size_t)(f >> 6) * BB + b) * 64 + (f & 63)];
        f = tid + 512;
        zb4[f] = ((const float4*)z)[((size_t)(f >> 6) * BB + b) * 64 + (f & 63)];
    }
    __syncthreads();
    const float4* wr = (const float4*)(Wg + (size_t)tid * DG);
    float acc[TT];
#pragma unroll
    for (int t = 0; t < TT; ++t) acc[t] = 0.f;
    for (int c4 = 0; c4 < 64; ++c4) {
        float4 w = wr[c4];
#pragma unroll
        for (int t = 0; t < TT; ++t) {
            float4 zz = zb4[(t << 6) + c4];
            acc[t] += w.x * zz.x + w.y * zz.y + w.z * zz.z + w.w * zz.w;
        }
    }
#pragma unroll
    for (int t = 0; t < TT; ++t)
        zp[((size_t)t * BB + b) * DH + tid] = acc[t];
}

// ---------- kernel 2: recurrence. Output-strip matvec (no cross-block sum),
//            flag-based relaxed exchange, all-wave thread-per-dim settle ----------
__global__ __launch_bounds__(512, 2) void rnn5(
    const float* __restrict__ zp,      // [T][B][DH]
    const float* __restrict__ Wh,      // [DH][DH]
    const float* __restrict__ bh,
    const float* __restrict__ lng,
    const float* __restrict__ lnb,
    const float* __restrict__ alphap,
    const float* __restrict__ Whead,   // [DOUT][DH]
    const float* __restrict__ bhead,
    const float* __restrict__ clean,   // [B][DOUT]
    float* gpart,                      // [2][B][DH] assembled hb (strip-owned)
    int* flags,                        // [B][4] step-tagged, FPAD-spaced
    float* __restrict__ ssd, float* __restrict__ cosv)
{
    __shared__ __align__(16) float h_lds[DH];
    __shared__ __align__(16) float u_lds[(TT - 1) * DH];  // 30 KB rank-15 A factors
    __shared__ __align__(16) float mpart[4 * 128];
    __shared__ __align__(16) float ppart[DH];
    __shared__ float red[48];
    __shared__ float d_lds[16];
    __shared__ float cv_lds[16];

    const int tid  = threadIdx.x;
    const int b    = blockIdx.x & 63;   // blocks {b,b+64,b+128,b+192}: same XCD under %8 RR
    const int q    = blockIdx.x >> 6;   // output strip [128q, 128q+128)
    const int lane = tid & 63;
    const int wid  = tid >> 6;
    const int r    = tid & 127;         // row within strip
    const int kq   = tid >> 7;          // K-quarter

    const float al   = alphap[0];
    const float kexp = (al >= 0.f) ? (1.f + log1pf(expf(al)))
                                   : (1.f / (1.f + log1pf(expf(-al))));
    const float gj = lng[tid];
    const float bj = lnb[tid];
    int* flg = flags + b * 4 * FPAD;    // flag j at flg[j*FPAD]

    // ---- W_h strip: row (q<<7)+r, cols [kq<<7, kq<<7+128) -> 128 AGPRs ----
    float wa[128];
    {
        const float* src = Wh + (size_t)((q << 7) + r) * DH + (kq << 7);
#pragma unroll
        for (int k = 0; k < 128; k += 4) {
            float4 v = *(const float4*)(src + k);
            asm volatile("v_accvgpr_write_b32 %0, %1" : "=a"(wa[k + 0]) : "v"(v.x));
            asm volatile("v_accvgpr_write_b32 %0, %1" : "=a"(wa[k + 1]) : "v"(v.y));
            asm volatile("v_accvgpr_write_b32 %0, %1" : "=a"(wa[k + 2]) : "v"(v.z));
            asm volatile("v_accvgpr_write_b32 %0, %1" : "=a"(wa[k + 3]) : "v"(v.w));
        }
    }

    if (tid < 16) cv_lds[tid] = 0.f;
    __syncthreads();

    float hb, h;

#pragma unroll 1
    for (int t = 0; t < TT; ++t) {
        if (t > 0) {
            // ---- strip matvec: mpart[kq][r] = W[row, Kq] . h[Kq] ----
            float acc = 0.f;
#pragma unroll
            for (int k4 = 0; k4 < 32; ++k4) {
                float4 h4 = ((const float4*)h_lds)[(kq << 5) + k4];   // uniform broadcast
                float w0, w1, w2, w3;
                asm("v_accvgpr_read_b32 %0, %1" : "=v"(w0) : "a"(wa[4 * k4 + 0]));
                asm("v_accvgpr_read_b32 %0, %1" : "=v"(w1) : "a"(wa[4 * k4 + 1]));
                asm("v_accvgpr_read_b32 %0, %1" : "=v"(w2) : "a"(wa[4 * k4 + 2]));
                asm("v_accvgpr_read_b32 %0, %1" : "=v"(w3) : "a"(wa[4 * k4 + 3]));
                acc = fmaf(w0, h4.x, fmaf(w1, h4.y, fmaf(w2, h4.z, fmaf(w3, h4.w, acc))));
            }
            mpart[(kq << 7) + r] = acc;
            __syncthreads();   // B1
            if (tid < 128) {
                float m = ((mpart[tid] + mpart[128 + tid]) + (mpart[256 + tid] + mpart[384 + tid]))
                        + zp[((size_t)t * BB + b) * DH + (q << 7) + tid]
                        + bh[(q << 7) + tid];
                __hip_atomic_store(gpart + ((size_t)(t & 1) * BB + b) * DH + (q << 7) + tid, m,
                                   __ATOMIC_RELAXED, __HIP_MEMORY_SCOPE_AGENT);
            }
            __syncthreads();   // B2: vmcnt(0) drain -> strip at coherence point
            if (tid == 0)
                __hip_atomic_store(&flg[q * FPAD], t, __ATOMIC_RELAXED, __HIP_MEMORY_SCOPE_AGENT);
            if (tid >= 4 && tid < 7) {
                int j = (q + (tid - 3)) & 3;   // the 3 other strips
                while (__hip_atomic_load(&flg[j * FPAD], __ATOMIC_RELAXED, __HIP_MEMORY_SCOPE_AGENT) < t) {}
            }
            __syncthreads();   // B3: all strips ready
            hb = __hip_atomic_load(gpart + ((size_t)(t & 1) * BB + b) * DH + tid,
                                   __ATOMIC_RELAXED, __HIP_MEMORY_SCOPE_AGENT);
        } else {
            hb = zp[((size_t)t * BB + b) * DH + tid] + bh[tid];   // h0 = 0
        }

        // ---- base LN: thread-per-dim, wave partials + redundant combine ----
        float S_hb, S_hb2;
        {
            float s1 = hb, s2 = hb * hb;
#pragma unroll
            for (int m = 32; m > 0; m >>= 1) {
                s1 += __shfl_xor(s1, m, 64);
                s2 += __shfl_xor(s2, m, 64);
            }
            if (lane == 0) { red[wid * 2] = s1; red[wid * 2 + 1] = s2; }
            __syncthreads();   // B4
            s1 = 0.f; s2 = 0.f;
#pragma unroll
            for (int w = 0; w < 8; ++w) { s1 += red[w * 2]; s2 += red[w * 2 + 1]; }
            S_hb = s1; S_hb2 = s2;
            float mu  = s1 * (1.f / DH);
            float var = s2 * (1.f / DH) - mu * mu;
            h = fmaxf((hb - mu) * rsqrtf(var + 1e-5f) * gj + bj, 0.f);
            h_lds[tid] = h;
        }
        __syncthreads();       // B5: h published

        const bool fin = (t == TT - 1);
        const int  nu  = fin ? (TT - 1) : t;

        if (t > 0) {
#pragma unroll 1
            for (int s = 0; s < 3; ++s) {
                // ---- dots: wave w handles i = w, w+8 ----
                float4 ha = ((const float4*)h_lds)[2 * lane];
                float4 hc = ((const float4*)h_lds)[2 * lane + 1];
#pragma unroll
                for (int rep = 0; rep < 2; ++rep) {
                    int i = wid + (rep << 3);
                    if (i < nu) {
                        float4 u0 = *(const float4*)&u_lds[i * DH + 8 * lane];
                        float4 u1 = *(const float4*)&u_lds[i * DH + 8 * lane + 4];
                        float a = dot4(u0, ha) + dot4(u1, hc);
#pragma unroll
                        for (int m = 32; m > 0; m >>= 1) a += __shfl_xor(a, m, 64);
                        if (lane == 0) d_lds[i] = a * cv_lds[i];
                    }
                }
                __syncthreads();   // B6: d ready

                // ---- Ah[tid] + 5 fused sums ----
                float Ah = 0.f;
#pragma unroll
                for (int i = 0; i < TT - 1; ++i)
                    if (i < nu) Ah = fmaf(d_lds[i], u_lds[i * DH + tid], Ah);

                float hAh = h * Ah, AhAh = Ah * Ah, hbAh = hb * Ah, SAh = Ah, hh = h * h;
#pragma unroll
                for (int m = 32; m > 0; m >>= 1) {
                    hAh  += __shfl_xor(hAh,  m, 64);
                    AhAh += __shfl_xor(AhAh, m, 64);
                    hbAh += __shfl_xor(hbAh, m, 64);
                    SAh  += __shfl_xor(SAh,  m, 64);
                    hh   += __shfl_xor(hh,   m, 64);
                }
                if (lane == 0) {
                    red[wid * 5 + 0] = hAh;  red[wid * 5 + 1] = AhAh;
                    red[wid * 5 + 2] = hbAh; red[wid * 5 + 3] = SAh;
                    red[wid * 5 + 4] = hh;
                }
                __syncthreads();   // B7: partials ready
                hAh = 0.f; AhAh = 0.f; hbAh = 0.f; SAh = 0.f; hh = 0.f;
#pragma unroll
                for (int w = 0; w < 8; ++w) {
                    hAh  += red[w * 5 + 0];
                    AhAh += red[w * 5 + 1];
                    hbAh += red[w * 5 + 2];
                    SAh  += red[w * 5 + 3];
                    hh   += red[w * 5 + 4];
                }

                float aa, c1;
                if (!fin) {
                    float n1 = fmaxf(sqrtf(hh),   1e-6f);
                    float n2 = fmaxf(sqrtf(AhAh), 1e-6f);
                    float R  = fminf(fmaxf(hAh / (n1 * n2), 0.f), 1.f);
                    aa = 1.f - __builtin_amdgcn_exp2f(kexp * __builtin_amdgcn_logf(1.f - R));
                    c1 = 1.f - aa * aa;
                } else { aa = 1.f; c1 = 1.f; }

                float Sx   = c1 * S_hb + aa * SAh;
                float Sx2  = c1 * c1 * S_hb2 + 2.f * c1 * aa * hbAh + aa * aa * AhAh;
                float mu2  = Sx * (1.f / DH);
                float var2 = Sx2 * (1.f / DH) - mu2 * mu2;
                float rs2  = rsqrtf(var2 + 1e-5f);
                float x    = c1 * hb + aa * Ah;
                h = fmaxf((x - mu2) * rs2 * gj + bj, 0.f);
                h_lds[tid] = h;
                __syncthreads();   // B8: h updated
            }
        }
        if (!fin) {
            u_lds[t * DH + tid] = h;   // append Hebbian factor (read after next B1+)
            if (tid < TT - 1) {
                float cvv = cv_lds[tid];
                cv_lds[tid] = (tid < t) ? cvv * 0.95f : (tid == t ? 0.5f : cvv);
            }
        }
    }

    if (q != 0) return;

    // ---- head + per-batch loss partials (q==0 blocks only) ----
    {
        const int oj   = tid & 255;
        const int half = tid >> 8;
        const float4* wr = (const float4*)(Whead + (size_t)oj * DH + half * 256);
        const float4* hv = ((const float4*)h_lds) + half * 64;
        float acc = 0.f;
#pragma unroll 4
        for (int i4 = 0; i4 < 64; ++i4) {
            float4 w  = wr[i4];
            float4 h4 = hv[i4];
            acc += w.x * h4.x + w.y * h4.y + w.z * h4.z + w.w * h4.w;
        }
        ppart[tid] = acc;
        __syncthreads();

        float pred = 0.f, tg = 0.f;
        if (tid < DOUT) {
            pred = ppart[tid] + ppart[tid + 256] + bhead[tid];
            tg   = clean[(size_t)b * DOUT + tid];
        }
        float pss = blk_sum(pred * pred, red, tid);
        float tss = blk_sum(tg * tg, red, tid);
        float pn = pred / (sqrtf(pss) + 1e-6f);
        float tn = tg   / (sqrtf(tss) + 1e-6f);
        float dd = pn - tn;
        float2 lc = blk_sum2(dd * dd, pn * tn, red, tid);
        if (tid == 0) { ssd[b] = lc.x; cosv[b] = lc.y; }
    }
}

// ---------- kernel 3: reduce 64 batch partials -> (loss, cosine) ----------
__global__ __launch_bounds__(64) void finish_kernel(
    const float* __restrict__ ssd, const float* __restrict__ cosv,
    float* __restrict__ out)
{
    int tid = threadIdx.x;
    float a = ssd[tid];
    float c = cosv[tid];
#pragma unroll
    for (int off = 32; off > 0; off >>= 1) {
        a += __shfl_down(a, off, 64);
        c += __shfl_down(c, off, 64);
    }
    if (tid == 0) {
        out[0] = a / (float)(BB * DOUT);
        out[1] = c / (float)BB;
    }
}

extern "C" void kernel_launch(void* const* d_in, const int* in_sizes, int n_in,
                              void* d_out, int out_size, void* d_ws, size_t ws_size,
                              hipStream_t stream) {
    const float* z     = (const float*)d_in[0];
    const float* clean = (const float*)d_in[1];
    const float* Wh    = (const float*)d_in[2];
    const float* Wg    = (const float*)d_in[3];
    const float* bh    = (const float*)d_in[4];
    const float* lng   = (const float*)d_in[5];
    const float* lnb   = (const float*)d_in[6];
    const float* alpha = (const float*)d_in[7];
    const float* Whead = (const float*)d_in[8];
    const float* bhead = (const float*)d_in[9];
    float* out = (float*)d_out;

    float* zp    = (float*)d_ws;                       // 2 MB
    float* gpart = zp + (size_t)TT * BB * DH;          // [2][64][512] = 256 KB
    float* ssd   = gpart + (size_t)2 * BB * DH;        // 64
    float* cosv  = ssd + BB;                           // 64
    int*   flags = (int*)(cosv + BB);                  // 256*FPAD ints = 32 KB

    zproj2<<<BB, 512, 0, stream>>>(z, Wg, zp, flags);
    rnn5<<<4 * BB, 512, 0, stream>>>(zp, Wh, bh, lng, lnb, alpha,
                                     Whead, bhead, clean, gpart, flags, ssd, cosv);
    finish_kernel<<<1, 64, 0, stream>>>(ssd, cosv, out);
}

// Round 6
// 252.395 us; speedup vs baseline: 2.6850x; 1.0747x over previous
//
#include <hip/hip_runtime.h>
#include <math.h>

#define TT   16
#define BB   64
#define DG   256
#define DH   512
#define DOUT 256

typedef unsigned long long u64t;

__device__ __forceinline__ float dot4(float4 a, float4 b) {
    return fmaf(a.x, b.x, fmaf(a.y, b.y, fmaf(a.z, b.z, a.w * b.w)));
}

__device__ __forceinline__ float blk_sum(float v, float* red, int tid) {
#pragma unroll
    for (int off = 32; off > 0; off >>= 1) v += __shfl_down(v, off, 64);
    if ((tid & 63) == 0) red[tid >> 6] = v;
    __syncthreads();
    float s = ((red[0] + red[1]) + (red[2] + red[3])) +
              ((red[4] + red[5]) + (red[6] + red[7]));
    __syncthreads();
    return s;
}

__device__ __forceinline__ float2 blk_sum2(float a, float b, float* red, int tid) {
#pragma unroll
    for (int off = 32; off > 0; off >>= 1) {
        a += __shfl_down(a, off, 64);
        b += __shfl_down(b, off, 64);
    }
    if ((tid & 63) == 0) { red[tid >> 6] = a; red[8 + (tid >> 6)] = b; }
    __syncthreads();
    float sa = ((red[0] + red[1]) + (red[2] + red[3])) +
               ((red[4] + red[5]) + (red[6] + red[7]));
    float sb = ((red[8] + red[9]) + (red[10] + red[11])) +
               ((red[12] + red[13]) + (red[14] + red[15]));
    __syncthreads();
    return make_float2(sa, sb);
}

// ---------- the whole problem in ONE kernel: 256 blocks = 64 batches x 4 strips ----------
__global__ __launch_bounds__(512, 2) void rnn6(
    const float* __restrict__ z,      // [T][B][DG]
    const float* __restrict__ clean,  // [B][DOUT]
    const float* __restrict__ Wh,     // [DH][DH]
    const float* __restrict__ Wg,     // [DH][DG]
    const float* __restrict__ bh,
    const float* __restrict__ lng,
    const float* __restrict__ lnb,
    const float* __restrict__ alphap,
    const float* __restrict__ Whead,  // [DOUT][DH]
    const float* __restrict__ bhead,
    u64t* gpart,                      // [2][B][DH] tagged (tag<<32)|f32bits
    u64t* ssdp, u64t* cosp,           // [B] tagged loss partials
    float* __restrict__ out)
{
    __shared__ __align__(16) float u_lds[(TT - 1) * DH];  // 30 KB: u[i][dim]
    __shared__ __align__(16) float ut[(TT - 1) * DH];     // 30 KB: u_t[i][k][lane] (first 16KB aliased as z staging)
    __shared__ __align__(16) float zp_lds[TT * 128];      // 8 KB: zproj+bh for our strip
    __shared__ __align__(16) float h_lds[DH];             // h (dim-major, for matvec broadcast + head)
    __shared__ __align__(16) float ht[DH];                // h_t[k][lane] (for dots, conflict-free)
    __shared__ __align__(16) float mpart[512];
    __shared__ __align__(16) float ppart[DH];
    __shared__ float red[48];
    __shared__ float d_lds[16];
    __shared__ float cv_lds[16];

    const int tid  = threadIdx.x;
    const int b    = blockIdx.x & 63;
    const int q    = blockIdx.x >> 6;     // output strip [128q, 128q+128)
    const int lane = tid & 63;
    const int wid  = tid >> 6;

    // ---------------- prologue: zproj for our strip (folds kernel 1) ----------------
    {
        float* z_s = ut;                  // alias: 16 KB of ut holds z[:, b, :]
        for (int f = tid; f < TT * 64; f += 512)
            ((float4*)z_s)[f] = ((const float4*)z)[(size_t)(f >> 6) * (BB * 64) + b * 64 + (f & 63)];
        if (tid < 16) cv_lds[tid] = 0.f;
        __syncthreads();
        const int r  = tid & 127;
        const int tq = tid >> 7;          // 4 t's per thread, full 256-dot (no combine needed)
        const float4* wrow = (const float4*)(Wg + (size_t)((q << 7) + r) * DG);
        float a0 = 0.f, a1 = 0.f, a2 = 0.f, a3 = 0.f;
        for (int j = 0; j < 64; ++j) {
            float4 w = wrow[j];
            a0 += dot4(w, ((const float4*)z_s)[(4 * tq + 0) * 64 + j]);
            a1 += dot4(w, ((const float4*)z_s)[(4 * tq + 1) * 64 + j]);
            a2 += dot4(w, ((const float4*)z_s)[(4 * tq + 2) * 64 + j]);
            a3 += dot4(w, ((const float4*)z_s)[(4 * tq + 3) * 64 + j]);
        }
        float bhr = bh[(q << 7) + r];
        zp_lds[(4 * tq + 0) * 128 + r] = a0 + bhr;
        zp_lds[(4 * tq + 1) * 128 + r] = a1 + bhr;
        zp_lds[(4 * tq + 2) * 128 + r] = a2 + bhr;
        zp_lds[(4 * tq + 3) * 128 + r] = a3 + bhr;
        __syncthreads();                  // z_s (ut) free for reuse after this
    }

    const float al   = alphap[0];
    const float kexp = (al >= 0.f) ? (1.f + log1pf(expf(al)))
                                   : (1.f / (1.f + log1pf(expf(-al))));
    const float gj = lng[tid];
    const float bj = lnb[tid];

    // ---- W_h strip: row (q<<7)+(tid&127), cols [ (tid>>7)<<7 , +128 ) -> 128 AGPRs ----
    float wa[128];
    {
        const float* src = Wh + (size_t)((q << 7) + (tid & 127)) * DH + ((tid >> 7) << 7);
#pragma unroll
        for (int k = 0; k < 128; k += 4) {
            float4 v = *(const float4*)(src + k);
            asm volatile("v_accvgpr_write_b32 %0, %1" : "=a"(wa[k + 0]) : "v"(v.x));
            asm volatile("v_accvgpr_write_b32 %0, %1" : "=a"(wa[k + 1]) : "v"(v.y));
            asm volatile("v_accvgpr_write_b32 %0, %1" : "=a"(wa[k + 2]) : "v"(v.z));
            asm volatile("v_accvgpr_write_b32 %0, %1" : "=a"(wa[k + 3]) : "v"(v.w));
        }
    }

    float h = 0.f, hb = 0.f;

#pragma unroll 1
    for (int t = 0; t < TT; ++t) {
        // ---------------- matvec partials (t>0) ----------------
        if (t > 0) {
            const int kq = tid >> 7;
            float acc = 0.f;
#pragma unroll
            for (int k4 = 0; k4 < 32; ++k4) {
                float4 h4 = ((const float4*)h_lds)[(kq << 5) + k4];   // uniform broadcast
                float w0, w1, w2, w3;
                asm("v_accvgpr_read_b32 %0, %1" : "=v"(w0) : "a"(wa[4 * k4 + 0]));
                asm("v_accvgpr_read_b32 %0, %1" : "=v"(w1) : "a"(wa[4 * k4 + 1]));
                asm("v_accvgpr_read_b32 %0, %1" : "=v"(w2) : "a"(wa[4 * k4 + 2]));
                asm("v_accvgpr_read_b32 %0, %1" : "=v"(w3) : "a"(wa[4 * k4 + 3]));
                acc = fmaf(w0, h4.x, fmaf(w1, h4.y, fmaf(w2, h4.z, fmaf(w3, h4.w, acc))));
            }
            mpart[tid] = acc;             // tid == kq*128 + r
        }
        __syncthreads();                  // B1: mpart ready (and prev-step LDS quiesced)

        // ---------------- tagged exchange: data IS the flag ----------------
        const unsigned tag = (unsigned)(t + 1);
        u64t* gb = gpart + ((size_t)(t & 1) * BB + b) * DH;
        if (tid < 128) {
            float m = zp_lds[t * 128 + tid];
            if (t > 0)
                m += (mpart[tid] + mpart[tid + 128]) + (mpart[tid + 256] + mpart[tid + 384]);
            u64t pk = ((u64t)tag << 32) | (u64t)__float_as_uint(m);
            __hip_atomic_store(gb + (q << 7) + tid, pk, __ATOMIC_RELAXED, __HIP_MEMORY_SCOPE_AGENT);
        }
        if (t == TT - 1 && q != 0) return;   // non-head strips: contribution stored, done

        {   // poll own dim until this step's value lands (double-buffer + exact tag = race-free)
            u64t v = __hip_atomic_load(gb + tid, __ATOMIC_RELAXED, __HIP_MEMORY_SCOPE_AGENT);
            while ((unsigned)(v >> 32) != tag) {
                __builtin_amdgcn_s_sleep(1);
                v = __hip_atomic_load(gb + tid, __ATOMIC_RELAXED, __HIP_MEMORY_SCOPE_AGENT);
            }
            hb = __uint_as_float((unsigned)v);
        }

        // ---------------- base LN ----------------
        float S_hb, S_hb2;
        {
            float s1 = hb, s2 = hb * hb;
#pragma unroll
            for (int m = 32; m > 0; m >>= 1) {
                s1 += __shfl_xor(s1, m, 64);
                s2 += __shfl_xor(s2, m, 64);
            }
            if (lane == 0) { red[wid * 2] = s1; red[wid * 2 + 1] = s2; }
            __syncthreads();              // B4
            s1 = 0.f; s2 = 0.f;
#pragma unroll
            for (int w = 0; w < 8; ++w) { s1 += red[w * 2]; s2 += red[w * 2 + 1]; }
            S_hb = s1; S_hb2 = s2;
            float mu  = s1 * (1.f / DH);
            float var = s2 * (1.f / DH) - mu * mu;
            h = fmaxf((hb - mu) * rsqrtf(var + 1e-5f) * gj + bj, 0.f);
        }
        ht[(tid & 7) * 64 + (tid >> 3)] = h;       // h_t for dots (conflict-free reads)
        if (t == 0) {
            h_lds[tid] = h;
            u_lds[tid] = h;                        // u[0]
            ut[(tid & 7) * 64 + (tid >> 3)] = h;   // u_t[0]
        }
        __syncthreads();                  // B5: h_t (and t==0 publishes) visible

        // ---------------- settle (A=0 at t=0 -> identity, skipped) ----------------
        if (t > 0) {
            const bool fin = (t == TT - 1);
            const int  nu  = t;           // == 15 at fin
#pragma unroll 1
            for (int s = 0; s < 3; ++s) {
                // dots: wave w owns i = w, w+8; fully conflict-free transposed reads
#pragma unroll
                for (int rep = 0; rep < 2; ++rep) {
                    int i = wid + (rep << 3);
                    if (i < nu) {
                        float a = 0.f;
#pragma unroll
                        for (int k = 0; k < 8; ++k)
                            a = fmaf(ut[i * DH + k * 64 + lane], ht[k * 64 + lane], a);
#pragma unroll
                        for (int m = 32; m > 0; m >>= 1) a += __shfl_xor(a, m, 64);
                        if (lane == 0) d_lds[i] = a * cv_lds[i];
                    }
                }
                __syncthreads();          // B6: d ready

                float Ah = 0.f;
#pragma unroll
                for (int i = 0; i < TT - 1; ++i)
                    if (i < nu) Ah = fmaf(d_lds[i], u_lds[i * DH + tid], Ah);

                float hAh = h * Ah, AhAh = Ah * Ah, hbAh = hb * Ah, SAh = Ah, hh = h * h;
#pragma unroll
                for (int m = 32; m > 0; m >>= 1) {
                    hAh  += __shfl_xor(hAh,  m, 64);
                    AhAh += __shfl_xor(AhAh, m, 64);
                    hbAh += __shfl_xor(hbAh, m, 64);
                    SAh  += __shfl_xor(SAh,  m, 64);
                    hh   += __shfl_xor(hh,   m, 64);
                }
                if (lane == 0) {
                    red[wid * 5 + 0] = hAh;  red[wid * 5 + 1] = AhAh;
                    red[wid * 5 + 2] = hbAh; red[wid * 5 + 3] = SAh;
                    red[wid * 5 + 4] = hh;
                }
                __syncthreads();          // B7: partials ready
                hAh = 0.f; AhAh = 0.f; hbAh = 0.f; SAh = 0.f; hh = 0.f;
#pragma unroll
                for (int w = 0; w < 8; ++w) {
                    hAh  += red[w * 5 + 0];
                    AhAh += red[w * 5 + 1];
                    hbAh += red[w * 5 + 2];
                    SAh  += red[w * 5 + 3];
                    hh   += red[w * 5 + 4];
                }

                float aa, c1;
                if (!fin) {
                    float n1 = fmaxf(sqrtf(hh),   1e-6f);
                    float n2 = fmaxf(sqrtf(AhAh), 1e-6f);
                    float R  = fminf(fmaxf(hAh / (n1 * n2), 0.f), 1.f);
                    aa = 1.f - __builtin_amdgcn_exp2f(kexp * __builtin_amdgcn_logf(1.f - R));
                    c1 = 1.f - aa * aa;
                } else { aa = 1.f; c1 = 1.f; }

                float Sx   = c1 * S_hb + aa * SAh;
                float Sx2  = c1 * c1 * S_hb2 + 2.f * c1 * aa * hbAh + aa * aa * AhAh;
                float mu2  = Sx * (1.f / DH);
                float var2 = Sx2 * (1.f / DH) - mu2 * mu2;
                float rs2  = rsqrtf(var2 + 1e-5f);
                float x    = c1 * hb + aa * Ah;
                h = fmaxf((x - mu2) * rs2 * gj + bj, 0.f);

                ht[(tid & 7) * 64 + (tid >> 3)] = h;
                if (s == 2) {
                    h_lds[tid] = h;
                    if (!fin) {
                        u_lds[t * DH + tid] = h;
                        ut[t * DH + (tid & 7) * 64 + (tid >> 3)] = h;
                    }
                }
                __syncthreads();          // B8
            }
        }
        if (t < TT - 1 && tid < TT - 1) {
            float cvv = cv_lds[tid];
            cv_lds[tid] = (tid < t) ? cvv * 0.95f : (tid == t ? 0.5f : cvv);
        }
    }

    // ---------------- head + per-batch loss (q==0 blocks only reach here) ----------------
    {
        const int oj   = tid & 255;
        const int half = tid >> 8;
        const float4* wr = (const float4*)(Whead + (size_t)oj * DH + half * 256);
        const float4* hv = ((const float4*)h_lds) + half * 64;
        float acc = 0.f;
#pragma unroll 4
        for (int i4 = 0; i4 < 64; ++i4) {
            float4 w  = wr[i4];
            float4 h4 = hv[i4];
            acc += w.x * h4.x + w.y * h4.y + w.z * h4.z + w.w * h4.w;
        }
        ppart[tid] = acc;
        __syncthreads();

        float pred = 0.f, tg = 0.f;
        if (tid < DOUT) {
            pred = ppart[tid] + ppart[tid + 256] + bhead[tid];
            tg   = clean[(size_t)b * DOUT + tid];
        }
        float pss = blk_sum(pred * pred, red, tid);
        float tss = blk_sum(tg * tg, red, tid);
        float pn = pred / (sqrtf(pss) + 1e-6f);
        float tn = tg   / (sqrtf(tss) + 1e-6f);
        float dd = pn - tn;
        float2 lc = blk_sum2(dd * dd, pn * tn, red, tid);
        if (tid == 0) {
            u64t pk = ((u64t)81u << 32) | (u64t)__float_as_uint(lc.x);
            __hip_atomic_store(ssdp + b, pk, __ATOMIC_RELAXED, __HIP_MEMORY_SCOPE_AGENT);
            pk = ((u64t)81u << 32) | (u64t)__float_as_uint(lc.y);
            __hip_atomic_store(cosp + b, pk, __ATOMIC_RELAXED, __HIP_MEMORY_SCOPE_AGENT);
        }
    }

    // ---------------- finisher: block 0, wave 0 polls 64 tagged partials ----------------
    if (blockIdx.x == 0 && wid == 0) {
        u64t va = __hip_atomic_load(ssdp + lane, __ATOMIC_RELAXED, __HIP_MEMORY_SCOPE_AGENT);
        while ((unsigned)(va >> 32) != 81u) {
            __builtin_amdgcn_s_sleep(1);
            va = __hip_atomic_load(ssdp + lane, __ATOMIC_RELAXED, __HIP_MEMORY_SCOPE_AGENT);
        }
        u64t vc = __hip_atomic_load(cosp + lane, __ATOMIC_RELAXED, __HIP_MEMORY_SCOPE_AGENT);
        while ((unsigned)(vc >> 32) != 81u) {
            __builtin_amdgcn_s_sleep(1);
            vc = __hip_atomic_load(cosp + lane, __ATOMIC_RELAXED, __HIP_MEMORY_SCOPE_AGENT);
        }
        float a = __uint_as_float((unsigned)va);
        float c = __uint_as_float((unsigned)vc);
#pragma unroll
        for (int m = 32; m > 0; m >>= 1) {
            a += __shfl_xor(a, m, 64);
            c += __shfl_xor(c, m, 64);
        }
        if (lane == 0) {
            out[0] = a * (1.f / (BB * DOUT));
            out[1] = c * (1.f / BB);
        }
    }
}

extern "C" void kernel_launch(void* const* d_in, const int* in_sizes, int n_in,
                              void* d_out, int out_size, void* d_ws, size_t ws_size,
                              hipStream_t stream) {
    const float* z     = (const float*)d_in[0];
    const float* clean = (const float*)d_in[1];
    const float* Wh    = (const float*)d_in[2];
    const float* Wg    = (const float*)d_in[3];
    const float* bh    = (const float*)d_in[4];
    const float* lng   = (const float*)d_in[5];
    const float* lnb   = (const float*)d_in[6];
    const float* alpha = (const float*)d_in[7];
    const float* Whead = (const float*)d_in[8];
    const float* bhead = (const float*)d_in[9];
    float* out = (float*)d_out;

    u64t* gpart = (u64t*)d_ws;               // [2][64][512] u64 = 512 KB (poison tag 0xAAAAAAAA != any real tag)
    u64t* ssdp  = gpart + (size_t)2 * BB * DH;
    u64t* cosp  = ssdp + BB;

    rnn6<<<4 * BB, 512, 0, stream>>>(z, clean, Wh, Wg, bh, lng, lnb, alpha,
                                     Whead, bhead, gpart, ssdp, cosp, out);
}